// Round 10
// baseline (358.582 us; speedup 1.0000x reference)
//
#include <hip/hip_runtime.h>

#define BB 4
#define CC 17
#define NN 4096
#define KN 7
#define NPTS (BB*NN)             // 16384
#define PAIRS (NPTS*KN)          // 114688
#define TT (CC*CC)               // 289
#define FINF 3.4e38f
#define NWV 4                    // waves per knn block
#define CSW 1024                 // candidates per wave-slice
#define NTW (CSW/16)             // 64 tiles per wave
#define RPB 16                   // rows per knn block
#define SCAP 96                  // per-row survivor cap
#define SPAD 97                  // 97 mod 32 = 1 -> P3 banks (row+s)%32
#define TDW 160                  // bf16 T row: 320 elems = 160 dwords
#define PF 16                    // prefetch depth (register ring)

typedef float f32x4 __attribute__((ext_vector_type(4)));
typedef short short8 __attribute__((ext_vector_type(8)));

__device__ __forceinline__ unsigned int rne_bf16(float x) {
    unsigned int u = __float_as_uint(x);
    return (u + 0x7FFFu + ((u >> 16) & 1u)) >> 16;
}

__device__ __forceinline__ bool lexless(float ad, int ai, float bd, int bi) {
    return (ad < bd) || (ad == bd && ai < bi);
}

// ---- Stage 1: logits -> xs fp32[.][24], xbA/xbB bf16[.][32] (norm folded), sq
__global__ __launch_bounds__(256) void prep_kernel(const float* __restrict__ logits,
                                                   float* __restrict__ xs,
                                                   unsigned short* __restrict__ xbA,
                                                   unsigned short* __restrict__ xbB,
                                                   float* __restrict__ sq) {
    int i = blockIdx.x * blockDim.x + threadIdx.x;
    if (i >= NPTS) return;
    int b = i >> 12;
    int n = i & (NN - 1);
    const float* base = logits + (size_t)b * CC * NN + n;
    float v[24];
    float s = 0.f;
#pragma unroll
    for (int c = 0; c < CC; ++c) { v[c] = base[(size_t)c * NN]; s = fmaf(v[c], v[c], s); }
#pragma unroll
    for (int c = CC; c < 24; ++c) v[c] = 0.f;
    float4* dst = (float4*)(xs + (size_t)i * 24);
#pragma unroll
    for (int q = 0; q < 6; ++q)
        dst[q] = make_float4(v[4*q], v[4*q+1], v[4*q+2], v[4*q+3]);
    sq[i] = s;

    unsigned int w[16];
#pragma unroll
    for (int t = 0; t < 8; ++t)
        w[t] = rne_bf16(v[2*t]) | (rne_bf16(v[2*t+1]) << 16);
#pragma unroll
    for (int t = 9; t < 16; ++t) w[t] = 0u;
    // A view: slot16 = v16, slot17 = 1.0
    w[8] = rne_bf16(v[16]) | (0x3F80u << 16);
    uint4* da = (uint4*)(xbA + (size_t)i * 32);
#pragma unroll
    for (int q = 0; q < 4; ++q)
        da[q] = make_uint4(w[4*q], w[4*q+1], w[4*q+2], w[4*q+3]);
    // B view: slot17 = -sq/2  => mfma acc = dot - sq_c/2, rank = -2*acc
    w[8] = rne_bf16(v[16]) | (rne_bf16(-0.5f * s) << 16);
    uint4* db = (uint4*)(xbB + (size_t)i * 32);
#pragma unroll
    for (int q = 0; q < 4; ++q)
        db[q] = make_uint4(w[4*q], w[4*q+1], w[4*q+2], w[4*q+3]);
}

// ---- Stage 1b: insT fp32[16384][289] -> Tb bf16[16384][320] ----------------
__global__ __launch_bounds__(256) void prepT_kernel(const float* __restrict__ insT,
                                                    unsigned int* __restrict__ Tb) {
    int i = blockIdx.x * 256 + threadIdx.x;
    int row = i / TDW;
    int dw  = i - row * TDW;
    int e   = dw * 2;
    const float* src = insT + (size_t)row * TT;
    float v0 = (e     < TT) ? src[e]     : 0.f;
    float v1 = (e + 1 < TT) ? src[e + 1] : 0.f;
    Tb[i] = rne_bf16(v0) | (rne_bf16(v1) << 16);
}

// ---- Stage 2: fused kNN, 16-deep explicit prefetch pipeline ----------------
// Block = 16 rows x 4 waves x 1024-cand slices.
// P1: MFMA sweep, per-lane max-acc -> per-wave 8th-largest bound (flat rank).
// P2: athr = max wave-bounds - margin; re-sweep -> u32 masks -> popc append.
// P3a: fp32 exact rank of survivors (16 thr/row); P3b: 16-lane serial top-7.
__global__ __launch_bounds__(256, 4) void knn_kernel(const unsigned short* __restrict__ xbA,
                                                     const unsigned short* __restrict__ xbB,
                                                     const float* __restrict__ sq,
                                                     const float* __restrict__ xs,
                                                     int* __restrict__ nidx) {
    int tid   = threadIdx.x;
    int wid   = tid >> 6;
    int lane  = tid & 63;
    int strip = blockIdx.x;              // 0..1023
    int b     = strip >> 8;
    int cb    = b * NN + wid * CSW;
    int col   = lane & 15;
    int grp   = lane >> 4;
    int k0    = grp * 8;

    __shared__ float thr_lds[NWV][RPB];
    __shared__ int   scnt[RPB];
    __shared__ int   slist[RPB][SPAD];
    __shared__ float srank[RPB][SPAD];
    if (tid < RPB) scnt[tid] = 0;

    short8 A = *reinterpret_cast<const short8*>(xbA + (size_t)(strip * 16 + col) * 32 + k0);
    const unsigned short* bp = xbB + (size_t)(cb + col) * 32 + k0;
    f32x4 z = {0.f, 0.f, 0.f, 0.f};

    // ---- Pass 1: per-lane stream max of acc; 16 loads in flight ----
    short8 buf[PF];
#pragma unroll
    for (int p = 0; p < PF; ++p)
        buf[p] = *reinterpret_cast<const short8*>(bp + (size_t)p * 512);
    float mx[4] = {-FINF, -FINF, -FINF, -FINF};
#pragma unroll
    for (int t = 0; t < NTW; ++t) {
        f32x4 acc = __builtin_amdgcn_mfma_f32_16x16x32_bf16(A, buf[t & (PF - 1)], z, 0, 0, 0);
        if (t + PF < NTW)
            buf[t & (PF - 1)] = *reinterpret_cast<const short8*>(bp + (size_t)(t + PF) * 512);
#pragma unroll
        for (int j = 0; j < 4; ++j)
            mx[j] = fmaxf(mx[j], acc[j]);
    }
    // slice bound = 8th-largest of the 16 lane-maxes (flat rank count; valid low bound)
#pragma unroll
    for (int j = 0; j < 4; ++j) {
        float v = mx[j];
        int cnt = 0;
#pragma unroll
        for (int m = 1; m < 16; ++m) {
            float o = __shfl_xor(v, m);
            cnt += (o > v) ? 1 : 0;
        }
        float bv = (cnt <= 7) ? v : FINF;
        bv = fminf(bv, __shfl_xor(bv, 1));
        bv = fminf(bv, __shfl_xor(bv, 2));
        bv = fminf(bv, __shfl_xor(bv, 4));
        bv = fminf(bv, __shfl_xor(bv, 8));
        if (col == 0) thr_lds[wid][grp * 4 + j] = bv;
    }
    __syncthreads();

    // ---- Pass 2: acc-threshold re-sweep, same prefetch pipeline ----
    float athr[4];
#pragma unroll
    for (int j = 0; j < 4; ++j) {
        int rr = grp * 4 + j;
        float m = -FINF;
#pragma unroll
        for (int w = 0; w < NWV; ++w) m = fmaxf(m, thr_lds[w][rr]);
        athr[j] = m - (0.35f + 0.007f * fabsf(m));   // bf16-error cover (acc units)
    }
    unsigned int msk[2][4] = {{0u,0u,0u,0u},{0u,0u,0u,0u}};
#pragma unroll
    for (int p = 0; p < PF; ++p)
        buf[p] = *reinterpret_cast<const short8*>(bp + (size_t)p * 512);
#pragma unroll
    for (int t = 0; t < NTW; ++t) {
        f32x4 acc = __builtin_amdgcn_mfma_f32_16x16x32_bf16(A, buf[t & (PF - 1)], z, 0, 0, 0);
        if (t + PF < NTW)
            buf[t & (PF - 1)] = *reinterpret_cast<const short8*>(bp + (size_t)(t + PF) * 512);
#pragma unroll
        for (int j = 0; j < 4; ++j)
            msk[t >> 5][j] |= (acc[j] > athr[j]) ? (1u << (t & 31)) : 0u;
    }
#pragma unroll
    for (int h2 = 0; h2 < 2; ++h2) {
#pragma unroll
        for (int j = 0; j < 4; ++j) {
            unsigned int w = msk[h2][j];
            int nb = __popc(w);
            if (nb) {
                int rloc = grp * 4 + j;
                int base = atomicAdd(&scnt[rloc], nb);
                while (w) {
                    int t = __ffs(w) - 1; w &= w - 1;
                    if (base < SCAP) slist[rloc][base] = cb + (h2 * 32 + t) * 16 + col;
                    ++base;
                }
            }
        }
    }
    __syncthreads();

    // ---- Pass 3a: exact fp32 rank of survivors; 16 threads per row ----
    {
        int row  = tid >> 4;
        int l16  = tid & 15;
        int rowg = strip * 16 + row;
        int cnt  = scnt[row]; cnt = (cnt > SCAP) ? SCAP : cnt;
        const float4* qp = (const float4*)(xs + (size_t)rowg * 24);
        float qv[20];
#pragma unroll
        for (int c = 0; c < 5; ++c) {
            float4 t = qp[c];
            qv[4*c] = t.x; qv[4*c+1] = t.y; qv[4*c+2] = t.z; qv[4*c+3] = t.w;
        }
#pragma unroll
        for (int h = 0; h < 6; ++h) {
            int slot = l16 + 16 * h;
            if (slot < cnt) {
                int g = slist[row][slot];
                const float4* xp = (const float4*)(xs + (size_t)g * 24);
                float dot = 0.f;
#pragma unroll
                for (int c = 0; c < 5; ++c) {
                    float4 xv = xp[c];
                    dot = fmaf(qv[4*c+0], xv.x, dot);
                    dot = fmaf(qv[4*c+1], xv.y, dot);
                    dot = fmaf(qv[4*c+2], xv.z, dot);
                    dot = fmaf(qv[4*c+3], xv.w, dot);
                }
                float r = fmaf(-2.f, dot, sq[g]);
                if (g == rowg) r = FINF;     // drop self by identity
                srank[row][slot] = r;
            }
        }
    }
    __syncthreads();

    // ---- Pass 3b: 16 lanes (lane = row), serial top-7 over cnt entries ----
    if (tid < RPB) {
        int row  = tid;
        int rowg = strip * 16 + row;
        int cnt  = scnt[row]; cnt = (cnt > SCAP) ? SCAP : cnt;
        float bd[KN]; int bi[KN];
#pragma unroll
        for (int k = 0; k < KN; ++k) { bd[k] = FINF; bi[k] = rowg; }
        for (int s = 0; s < cnt; ++s) {
            float r = srank[row][s];
            int   g = slist[row][s];
            if (lexless(r, g, bd[KN-1], bi[KN-1])) {
                bd[KN-1] = r; bi[KN-1] = g;
#pragma unroll
                for (int k = KN - 1; k >= 1; --k) {
                    if (lexless(bd[k], bi[k], bd[k-1], bi[k-1])) {
                        float td = bd[k]; bd[k] = bd[k-1]; bd[k-1] = td;
                        int   ti = bi[k]; bi[k] = bi[k-1]; bi[k-1] = ti;
                    }
                }
            }
        }
#pragma unroll
        for (int k = 0; k < KN; ++k)
            nidx[(size_t)rowg * KN + k] = bi[k];
    }
}

// ---- Stage 3: wave-per-row pair terms, bf16 T rows, hoisted loads ----------
__global__ __launch_bounds__(256) void pairb_kernel(const float* __restrict__ xs,
                                                    const int* __restrict__ labels,
                                                    const unsigned int* __restrict__ Tb,
                                                    const int* __restrict__ nidx,
                                                    double* __restrict__ partials) {
    int wid  = threadIdx.x >> 6;
    int lane = threadIdx.x & 63;
    int row  = blockIdx.x * 4 + wid;
    int li   = labels[row];

    const unsigned int* Ti = Tb + (size_t)row * TDW;
    unsigned int a0 = Ti[lane];
    unsigned int a1 = Ti[lane + 64];
    unsigned int a2 = (lane < 32) ? Ti[lane + 128] : 0u;
    float xi = (lane < 20) ? xs[(size_t)row * 24 + lane] : 0.f;

    int jn[KN];
#pragma unroll
    for (int kk = 0; kk < KN; ++kk) jn[kk] = nidx[(size_t)row * KN + kk];

    unsigned int bv[KN][3];
    float xj[KN];
#pragma unroll
    for (int kk = 0; kk < KN; ++kk) {
        const unsigned int* Tj = Tb + (size_t)jn[kk] * TDW;
        bv[kk][0] = Tj[lane];
        bv[kk][1] = Tj[lane + 64];
        bv[kk][2] = (lane < 32) ? Tj[lane + 128] : 0u;
        xj[kk] = (lane < 20) ? xs[(size_t)jn[kk] * 24 + lane] : 0.f;
    }

    double acc = 0.0;
#pragma unroll
    for (int kk = 0; kk < KN; ++kk) {
        float td = 0.f;
        unsigned int aw[3] = {a0, a1, a2};
#pragma unroll
        for (int q = 0; q < 3; ++q) {
            unsigned int a = aw[q], bb = bv[kk][q];
            float dlo = __uint_as_float(a << 16)         - __uint_as_float(bb << 16);
            float dhi = __uint_as_float(a & 0xFFFF0000u) - __uint_as_float(bb & 0xFFFF0000u);
            td = fmaf(dlo, dlo, td);
            td = fmaf(dhi, dhi, td);
        }
        float df = xi - xj[kk];
        float dp = df * df;
#pragma unroll
        for (int off = 32; off >= 1; off >>= 1) {
            td += __shfl_xor(td, off);
            dp += __shfl_xor(dp, off);
        }
        if (lane == 0) {
            float eij = expf(-0.5f * dp);
            float sgn = (labels[jn[kk]] == li) ? eij : -eij;
            acc += (double)sgn * (double)td;
        }
    }
    __shared__ double wsum[4];
    if (lane == 0) wsum[wid] = acc;
    __syncthreads();
    if (threadIdx.x == 0)
        partials[blockIdx.x] = wsum[0] + wsum[1] + wsum[2] + wsum[3];
}

// ---- Stage 3': fp32 fallback (small workspace) -----------------------------
__global__ __launch_bounds__(256) void pair_f32_kernel(const float* __restrict__ xs,
                                                       const int* __restrict__ labels,
                                                       const float* __restrict__ insT,
                                                       const int* __restrict__ nidx,
                                                       double* __restrict__ partials) {
    int wid  = threadIdx.x >> 6;
    int lane = threadIdx.x & 63;
    int row  = blockIdx.x * 4 + wid;
    int li   = labels[row];
    const float* Ti = insT + (size_t)row * TT;
    float tiv[5];
#pragma unroll
    for (int q = 0; q < 5; ++q) {
        int e = lane + 64 * q;
        tiv[q] = (e < TT) ? Ti[e] : 0.f;
    }
    float xi = (lane < 20) ? xs[(size_t)row * 24 + lane] : 0.f;
    double acc = 0.0;
#pragma unroll 1
    for (int kk = 0; kk < KN; ++kk) {
        int j = nidx[(size_t)row * KN + kk];
        const float* Tj = insT + (size_t)j * TT;
        float td = 0.f;
#pragma unroll
        for (int q = 0; q < 5; ++q) {
            int e = lane + 64 * q;
            if (e < TT) { float df = tiv[q] - Tj[e]; td = fmaf(df, df, td); }
        }
        float dp = 0.f;
        if (lane < 20) { float df = xi - xs[(size_t)j * 24 + lane]; dp = df * df; }
#pragma unroll
        for (int off = 32; off >= 1; off >>= 1) {
            td += __shfl_xor(td, off);
            dp += __shfl_xor(dp, off);
        }
        if (lane == 0) {
            float eij = expf(-0.5f * dp);
            float sgn = (labels[j] == li) ? eij : -eij;
            acc += (double)sgn * (double)td;
        }
    }
    __shared__ double wsum[4];
    if (lane == 0) wsum[wid] = acc;
    __syncthreads();
    if (threadIdx.x == 0)
        partials[blockIdx.x] = wsum[0] + wsum[1] + wsum[2] + wsum[3];
}

// ---- Stage 4: deterministic final reduce + mean ----------------------------
__global__ __launch_bounds__(1024) void finalize_kernel(const double* __restrict__ partials,
                                                        int nparts, float* __restrict__ out) {
    __shared__ double red[1024];
    int t = threadIdx.x;
    double s = 0.0;
    for (int q = t; q < nparts; q += 1024) s += partials[q];
    red[t] = s;
    __syncthreads();
    for (int sft = 512; sft > 0; sft >>= 1) {
        if (t < sft) red[t] += red[t + sft];
        __syncthreads();
    }
    if (t == 0) out[0] = (float)(red[0] / (double)PAIRS);
}

extern "C" void kernel_launch(void* const* d_in, const int* in_sizes, int n_in,
                              void* d_out, int out_size, void* d_ws, size_t ws_size,
                              hipStream_t stream) {
    const float* logits = (const float*)d_in[0];
    const int*   labels = (const int*)d_in[1];
    const float* insT   = (const float*)d_in[2];
    float* out = (float*)d_out;

    // workspace layout (bytes)
    const size_t o_part = 0;                          // 32768
    const size_t o_nidx = 32768;                      // 458752
    const size_t o_sq   = o_nidx + 458752;            // 65536
    const size_t o_xs   = o_sq + 65536;               // 1572864
    const size_t o_xbA  = o_xs + 1572864;             // 1048576
    const size_t o_xbB  = o_xbA + 1048576;            // 1048576
    const size_t o_Tb   = o_xbB + 1048576;            // 10485760
    const size_t need_Tb = o_Tb + 10485760;           // ~14.7 MB

    char* ws = (char*)d_ws;
    double*         partials = (double*)(ws + o_part);
    int*            nidx     = (int*)(ws + o_nidx);
    float*          sq       = (float*)(ws + o_sq);
    float*          xs       = (float*)(ws + o_xs);
    unsigned short* xbA      = (unsigned short*)(ws + o_xbA);
    unsigned short* xbB      = (unsigned short*)(ws + o_xbB);
    unsigned int*   Tb       = (unsigned int*)(ws + o_Tb);

    bool useTb = (ws_size >= need_Tb);

    hipLaunchKernelGGL(prep_kernel, dim3(NPTS / 256), dim3(256), 0, stream,
                       logits, xs, xbA, xbB, sq);
    if (useTb)
        hipLaunchKernelGGL(prepT_kernel, dim3(NPTS * TDW / 256), dim3(256), 0, stream,
                           insT, Tb);
    hipLaunchKernelGGL(knn_kernel, dim3(NPTS / RPB), dim3(256), 0, stream,
                       xbA, xbB, sq, xs, nidx);
    if (useTb)
        hipLaunchKernelGGL(pairb_kernel, dim3(NPTS / 4), dim3(256), 0, stream,
                           xs, labels, Tb, nidx, partials);
    else
        hipLaunchKernelGGL(pair_f32_kernel, dim3(NPTS / 4), dim3(256), 0, stream,
                           xs, labels, insT, nidx, partials);
    hipLaunchKernelGGL(finalize_kernel, dim3(1), dim3(1024), 0, stream,
                       partials, NPTS / 4, out);
}

// Round 11
// 158.389 us; speedup vs baseline: 2.2639x; 2.2639x over previous
//
#include <hip/hip_runtime.h>

#define BB 4
#define CC 17
#define NN 4096
#define KN 7
#define NPTS (BB*NN)             // 16384
#define PAIRS (NPTS*KN)          // 114688
#define TT (CC*CC)               // 289
#define FINF 3.4e38f
#define NWV 8                    // waves per knn block
#define CSW 512                  // candidates per wave-slice
#define NTW (CSW/16)             // 32 tiles per wave
#define RPB 16                   // rows per knn block
#define SCAP 96                  // per-row survivor cap
#define SPAD 97                  // 97 mod 32 = 1 -> P3 banks (row+s)%32
#define TDW 160                  // bf16 T row: 320 elems = 160 dwords
#define PF 4                     // prefetch depth (16 VGPRs)

typedef float f32x4 __attribute__((ext_vector_type(4)));
typedef short short8 __attribute__((ext_vector_type(8)));

__device__ __forceinline__ unsigned int rne_bf16(float x) {
    unsigned int u = __float_as_uint(x);
    return (u + 0x7FFFu + ((u >> 16) & 1u)) >> 16;
}

__device__ __forceinline__ bool lexless(float ad, int ai, float bd, int bi) {
    return (ad < bd) || (ad == bd && ai < bi);
}

// ---- Stage 1: logits -> xs fp32[.][24], xbA/xbB bf16[.][32] (norm folded), sq
__global__ __launch_bounds__(256) void prep_kernel(const float* __restrict__ logits,
                                                   float* __restrict__ xs,
                                                   unsigned short* __restrict__ xbA,
                                                   unsigned short* __restrict__ xbB,
                                                   float* __restrict__ sq) {
    int i = blockIdx.x * blockDim.x + threadIdx.x;
    if (i >= NPTS) return;
    int b = i >> 12;
    int n = i & (NN - 1);
    const float* base = logits + (size_t)b * CC * NN + n;
    float v[24];
    float s = 0.f;
#pragma unroll
    for (int c = 0; c < CC; ++c) { v[c] = base[(size_t)c * NN]; s = fmaf(v[c], v[c], s); }
#pragma unroll
    for (int c = CC; c < 24; ++c) v[c] = 0.f;
    float4* dst = (float4*)(xs + (size_t)i * 24);
#pragma unroll
    for (int q = 0; q < 6; ++q)
        dst[q] = make_float4(v[4*q], v[4*q+1], v[4*q+2], v[4*q+3]);
    sq[i] = s;

    unsigned int w[16];
#pragma unroll
    for (int t = 0; t < 8; ++t)
        w[t] = rne_bf16(v[2*t]) | (rne_bf16(v[2*t+1]) << 16);
#pragma unroll
    for (int t = 9; t < 16; ++t) w[t] = 0u;
    // A view: slot16 = v16, slot17 = 1.0
    w[8] = rne_bf16(v[16]) | (0x3F80u << 16);
    uint4* da = (uint4*)(xbA + (size_t)i * 32);
#pragma unroll
    for (int q = 0; q < 4; ++q)
        da[q] = make_uint4(w[4*q], w[4*q+1], w[4*q+2], w[4*q+3]);
    // B view: slot17 = -sq/2  => mfma acc = dot - sq_c/2, rank = -2*acc
    w[8] = rne_bf16(v[16]) | (rne_bf16(-0.5f * s) << 16);
    uint4* db = (uint4*)(xbB + (size_t)i * 32);
#pragma unroll
    for (int q = 0; q < 4; ++q)
        db[q] = make_uint4(w[4*q], w[4*q+1], w[4*q+2], w[4*q+3]);
}

// ---- Stage 1b: insT fp32[16384][289] -> Tb bf16[16384][320] ----------------
__global__ __launch_bounds__(256) void prepT_kernel(const float* __restrict__ insT,
                                                    unsigned int* __restrict__ Tb) {
    int i = blockIdx.x * 256 + threadIdx.x;
    int row = i / TDW;
    int dw  = i - row * TDW;
    int e   = dw * 2;
    const float* src = insT + (size_t)row * TT;
    float v0 = (e     < TT) ? src[e]     : 0.f;
    float v1 = (e + 1 < TT) ? src[e + 1] : 0.f;
    Tb[i] = rne_bf16(v0) | (rne_bf16(v1) << 16);
}

// ---- Stage 2: fused kNN. Block = 16 rows x 8 waves x 512-cand slices. ------
// PF=4 register prefetch ring keeps 4 tile-loads in flight per wave.
// P1: MFMA sweep, per-lane max-acc -> per-wave 8th-largest bound (flat rank).
// P2: athr = max wave-bounds - margin; re-sweep -> u32 mask -> popc append.
// P3a: fp32 exact rank of survivors (32 thr/row); P3b: 16-lane serial top-7.
__global__ __launch_bounds__(512) void knn_kernel(const unsigned short* __restrict__ xbA,
                                                  const unsigned short* __restrict__ xbB,
                                                  const float* __restrict__ sq,
                                                  const float* __restrict__ xs,
                                                  int* __restrict__ nidx) {
    int tid   = threadIdx.x;
    int wid   = tid >> 6;
    int lane  = tid & 63;
    int strip = blockIdx.x;              // 0..1023
    int b     = strip >> 8;
    int cb    = b * NN + wid * CSW;
    int col   = lane & 15;
    int grp   = lane >> 4;
    int k0    = grp * 8;

    __shared__ float thr_lds[NWV][RPB];
    __shared__ int   scnt[RPB];
    __shared__ int   slist[RPB][SPAD];
    __shared__ float srank[RPB][SPAD];
    if (tid < RPB) scnt[tid] = 0;

    short8 A = *reinterpret_cast<const short8*>(xbA + (size_t)(strip * 16 + col) * 32 + k0);
    const unsigned short* bp = xbB + (size_t)(cb + col) * 32 + k0;
    f32x4 z = {0.f, 0.f, 0.f, 0.f};

    // ---- Pass 1: per-lane stream max of acc; PF loads in flight ----
    short8 buf[PF];
#pragma unroll
    for (int p = 0; p < PF; ++p)
        buf[p] = *reinterpret_cast<const short8*>(bp + (size_t)p * 512);
    float mx[4] = {-FINF, -FINF, -FINF, -FINF};
#pragma unroll
    for (int t = 0; t < NTW; ++t) {
        short8 cur = buf[t & (PF - 1)];
        if (t + PF < NTW)
            buf[t & (PF - 1)] = *reinterpret_cast<const short8*>(bp + (size_t)(t + PF) * 512);
        f32x4 acc = __builtin_amdgcn_mfma_f32_16x16x32_bf16(A, cur, z, 0, 0, 0);
#pragma unroll
        for (int j = 0; j < 4; ++j)
            mx[j] = fmaxf(mx[j], acc[j]);
    }
    // slice bound = 8th-largest of the 16 lane-maxes (valid lower bound on row 8th acc)
#pragma unroll
    for (int j = 0; j < 4; ++j) {
        float v = mx[j];
        int cnt = 0;
#pragma unroll
        for (int m = 1; m < 16; ++m) {
            float o = __shfl_xor(v, m);
            cnt += (o > v) ? 1 : 0;
        }
        float bv = (cnt <= 7) ? v : FINF;
        bv = fminf(bv, __shfl_xor(bv, 1));
        bv = fminf(bv, __shfl_xor(bv, 2));
        bv = fminf(bv, __shfl_xor(bv, 4));
        bv = fminf(bv, __shfl_xor(bv, 8));
        if (col == 0) thr_lds[wid][grp * 4 + j] = bv;
    }
    __syncthreads();

    // ---- Pass 2: acc-threshold re-sweep, same prefetch ring ----
    float athr[4];
#pragma unroll
    for (int j = 0; j < 4; ++j) {
        int rr = grp * 4 + j;
        float m = -FINF;
#pragma unroll
        for (int w = 0; w < NWV; ++w) m = fmaxf(m, thr_lds[w][rr]);
        athr[j] = m - (0.35f + 0.007f * fabsf(m));   // bf16-error cover (acc units)
    }
    unsigned int msk[4] = {0u, 0u, 0u, 0u};
#pragma unroll
    for (int p = 0; p < PF; ++p)
        buf[p] = *reinterpret_cast<const short8*>(bp + (size_t)p * 512);
#pragma unroll
    for (int t = 0; t < NTW; ++t) {
        short8 cur = buf[t & (PF - 1)];
        if (t + PF < NTW)
            buf[t & (PF - 1)] = *reinterpret_cast<const short8*>(bp + (size_t)(t + PF) * 512);
        f32x4 acc = __builtin_amdgcn_mfma_f32_16x16x32_bf16(A, cur, z, 0, 0, 0);
#pragma unroll
        for (int j = 0; j < 4; ++j)
            msk[j] |= (acc[j] > athr[j]) ? (1u << t) : 0u;
    }
#pragma unroll
    for (int j = 0; j < 4; ++j) {
        unsigned int w = msk[j];
        int nb = __popc(w);
        if (nb) {
            int rloc = grp * 4 + j;
            int base = atomicAdd(&scnt[rloc], nb);
            while (w) {
                int t = __ffs(w) - 1; w &= w - 1;
                if (base < SCAP) slist[rloc][base] = cb + t * 16 + col;
                ++base;
            }
        }
    }
    __syncthreads();

    // ---- Pass 3a: exact fp32 rank of survivors; 32 threads per row ----
    {
        int row  = tid >> 5;                 // 0..15
        int l32  = tid & 31;
        int rowg = strip * 16 + row;
        int cnt  = scnt[row]; cnt = (cnt > SCAP) ? SCAP : cnt;
        const float4* qp = (const float4*)(xs + (size_t)rowg * 24);
        float qv[20];
#pragma unroll
        for (int c = 0; c < 5; ++c) {
            float4 t = qp[c];
            qv[4*c] = t.x; qv[4*c+1] = t.y; qv[4*c+2] = t.z; qv[4*c+3] = t.w;
        }
#pragma unroll
        for (int h = 0; h < 3; ++h) {
            int slot = l32 + 32 * h;
            if (slot < cnt) {
                int g = slist[row][slot];
                const float4* xp = (const float4*)(xs + (size_t)g * 24);
                float dot = 0.f;
#pragma unroll
                for (int c = 0; c < 5; ++c) {
                    float4 xv = xp[c];
                    dot = fmaf(qv[4*c+0], xv.x, dot);
                    dot = fmaf(qv[4*c+1], xv.y, dot);
                    dot = fmaf(qv[4*c+2], xv.z, dot);
                    dot = fmaf(qv[4*c+3], xv.w, dot);
                }
                float r = fmaf(-2.f, dot, sq[g]);
                if (g == rowg) r = FINF;     // drop self by identity
                srank[row][slot] = r;
            }
        }
    }
    __syncthreads();

    // ---- Pass 3b: 16 lanes (lane = row), serial top-7 over cnt entries ----
    if (tid < RPB) {
        int row  = tid;
        int rowg = strip * 16 + row;
        int cnt  = scnt[row]; cnt = (cnt > SCAP) ? SCAP : cnt;
        float bd[KN]; int bi[KN];
#pragma unroll
        for (int k = 0; k < KN; ++k) { bd[k] = FINF; bi[k] = rowg; }
        for (int s = 0; s < cnt; ++s) {
            float r = srank[row][s];
            int   g = slist[row][s];
            if (lexless(r, g, bd[KN-1], bi[KN-1])) {
                bd[KN-1] = r; bi[KN-1] = g;
#pragma unroll
                for (int k = KN - 1; k >= 1; --k) {
                    if (lexless(bd[k], bi[k], bd[k-1], bi[k-1])) {
                        float td = bd[k]; bd[k] = bd[k-1]; bd[k-1] = td;
                        int   ti = bi[k]; bi[k] = bi[k-1]; bi[k-1] = ti;
                    }
                }
            }
        }
#pragma unroll
        for (int k = 0; k < KN; ++k)
            nidx[(size_t)rowg * KN + k] = bi[k];
    }
}

// ---- Stage 3: wave-per-row pair terms, bf16 T rows, hoisted loads ----------
__global__ __launch_bounds__(256) void pairb_kernel(const float* __restrict__ xs,
                                                    const int* __restrict__ labels,
                                                    const unsigned int* __restrict__ Tb,
                                                    const int* __restrict__ nidx,
                                                    double* __restrict__ partials) {
    int wid  = threadIdx.x >> 6;
    int lane = threadIdx.x & 63;
    int row  = blockIdx.x * 4 + wid;
    int li   = labels[row];

    const unsigned int* Ti = Tb + (size_t)row * TDW;
    unsigned int a0 = Ti[lane];
    unsigned int a1 = Ti[lane + 64];
    unsigned int a2 = (lane < 32) ? Ti[lane + 128] : 0u;
    float xi = (lane < 20) ? xs[(size_t)row * 24 + lane] : 0.f;

    int jn[KN];
#pragma unroll
    for (int kk = 0; kk < KN; ++kk) jn[kk] = nidx[(size_t)row * KN + kk];

    unsigned int bv[KN][3];
    float xj[KN];
#pragma unroll
    for (int kk = 0; kk < KN; ++kk) {
        const unsigned int* Tj = Tb + (size_t)jn[kk] * TDW;
        bv[kk][0] = Tj[lane];
        bv[kk][1] = Tj[lane + 64];
        bv[kk][2] = (lane < 32) ? Tj[lane + 128] : 0u;
        xj[kk] = (lane < 20) ? xs[(size_t)jn[kk] * 24 + lane] : 0.f;
    }

    double acc = 0.0;
#pragma unroll
    for (int kk = 0; kk < KN; ++kk) {
        float td = 0.f;
        unsigned int aw[3] = {a0, a1, a2};
#pragma unroll
        for (int q = 0; q < 3; ++q) {
            unsigned int a = aw[q], bb = bv[kk][q];
            float dlo = __uint_as_float(a << 16)         - __uint_as_float(bb << 16);
            float dhi = __uint_as_float(a & 0xFFFF0000u) - __uint_as_float(bb & 0xFFFF0000u);
            td = fmaf(dlo, dlo, td);
            td = fmaf(dhi, dhi, td);
        }
        float df = xi - xj[kk];
        float dp = df * df;
#pragma unroll
        for (int off = 32; off >= 1; off >>= 1) {
            td += __shfl_xor(td, off);
            dp += __shfl_xor(dp, off);
        }
        if (lane == 0) {
            float eij = expf(-0.5f * dp);
            float sgn = (labels[jn[kk]] == li) ? eij : -eij;
            acc += (double)sgn * (double)td;
        }
    }
    __shared__ double wsum[4];
    if (lane == 0) wsum[wid] = acc;
    __syncthreads();
    if (threadIdx.x == 0)
        partials[blockIdx.x] = wsum[0] + wsum[1] + wsum[2] + wsum[3];
}

// ---- Stage 3': fp32 fallback (small workspace) -----------------------------
__global__ __launch_bounds__(256) void pair_f32_kernel(const float* __restrict__ xs,
                                                       const int* __restrict__ labels,
                                                       const float* __restrict__ insT,
                                                       const int* __restrict__ nidx,
                                                       double* __restrict__ partials) {
    int wid  = threadIdx.x >> 6;
    int lane = threadIdx.x & 63;
    int row  = blockIdx.x * 4 + wid;
    int li   = labels[row];
    const float* Ti = insT + (size_t)row * TT;
    float tiv[5];
#pragma unroll
    for (int q = 0; q < 5; ++q) {
        int e = lane + 64 * q;
        tiv[q] = (e < TT) ? Ti[e] : 0.f;
    }
    float xi = (lane < 20) ? xs[(size_t)row * 24 + lane] : 0.f;
    double acc = 0.0;
#pragma unroll 1
    for (int kk = 0; kk < KN; ++kk) {
        int j = nidx[(size_t)row * KN + kk];
        const float* Tj = insT + (size_t)j * TT;
        float td = 0.f;
#pragma unroll
        for (int q = 0; q < 5; ++q) {
            int e = lane + 64 * q;
            if (e < TT) { float df = tiv[q] - Tj[e]; td = fmaf(df, df, td); }
        }
        float dp = 0.f;
        if (lane < 20) { float df = xi - xs[(size_t)j * 24 + lane]; dp = df * df; }
#pragma unroll
        for (int off = 32; off >= 1; off >>= 1) {
            td += __shfl_xor(td, off);
            dp += __shfl_xor(dp, off);
        }
        if (lane == 0) {
            float eij = expf(-0.5f * dp);
            float sgn = (labels[j] == li) ? eij : -eij;
            acc += (double)sgn * (double)td;
        }
    }
    __shared__ double wsum[4];
    if (lane == 0) wsum[wid] = acc;
    __syncthreads();
    if (threadIdx.x == 0)
        partials[blockIdx.x] = wsum[0] + wsum[1] + wsum[2] + wsum[3];
}

// ---- Stage 4: deterministic final reduce + mean ----------------------------
__global__ __launch_bounds__(1024) void finalize_kernel(const double* __restrict__ partials,
                                                        int nparts, float* __restrict__ out) {
    __shared__ double red[1024];
    int t = threadIdx.x;
    double s = 0.0;
    for (int q = t; q < nparts; q += 1024) s += partials[q];
    red[t] = s;
    __syncthreads();
    for (int sft = 512; sft > 0; sft >>= 1) {
        if (t < sft) red[t] += red[t + sft];
        __syncthreads();
    }
    if (t == 0) out[0] = (float)(red[0] / (double)PAIRS);
}

extern "C" void kernel_launch(void* const* d_in, const int* in_sizes, int n_in,
                              void* d_out, int out_size, void* d_ws, size_t ws_size,
                              hipStream_t stream) {
    const float* logits = (const float*)d_in[0];
    const int*   labels = (const int*)d_in[1];
    const float* insT   = (const float*)d_in[2];
    float* out = (float*)d_out;

    // workspace layout (bytes)
    const size_t o_part = 0;                          // 32768
    const size_t o_nidx = 32768;                      // 458752
    const size_t o_sq   = o_nidx + 458752;            // 65536
    const size_t o_xs   = o_sq + 65536;               // 1572864
    const size_t o_xbA  = o_xs + 1572864;             // 1048576
    const size_t o_xbB  = o_xbA + 1048576;            // 1048576
    const size_t o_Tb   = o_xbB + 1048576;            // 10485760
    const size_t need_Tb = o_Tb + 10485760;           // ~14.7 MB

    char* ws = (char*)d_ws;
    double*         partials = (double*)(ws + o_part);
    int*            nidx     = (int*)(ws + o_nidx);
    float*          sq       = (float*)(ws + o_sq);
    float*          xs       = (float*)(ws + o_xs);
    unsigned short* xbA      = (unsigned short*)(ws + o_xbA);
    unsigned short* xbB      = (unsigned short*)(ws + o_xbB);
    unsigned int*   Tb       = (unsigned int*)(ws + o_Tb);

    bool useTb = (ws_size >= need_Tb);

    hipLaunchKernelGGL(prep_kernel, dim3(NPTS / 256), dim3(256), 0, stream,
                       logits, xs, xbA, xbB, sq);
    if (useTb)
        hipLaunchKernelGGL(prepT_kernel, dim3(NPTS * TDW / 256), dim3(256), 0, stream,
                           insT, Tb);
    hipLaunchKernelGGL(knn_kernel, dim3(NPTS / RPB), dim3(512), 0, stream,
                       xbA, xbB, sq, xs, nidx);
    if (useTb)
        hipLaunchKernelGGL(pairb_kernel, dim3(NPTS / 4), dim3(256), 0, stream,
                           xs, labels, Tb, nidx, partials);
    else
        hipLaunchKernelGGL(pair_f32_kernel, dim3(NPTS / 4), dim3(256), 0, stream,
                           xs, labels, insT, nidx, partials);
    hipLaunchKernelGGL(finalize_kernel, dim3(1), dim3(1024), 0, stream,
                       partials, NPTS / 4, out);
}

// Round 12
// 142.947 us; speedup vs baseline: 2.5085x; 1.1080x over previous
//
#include <hip/hip_runtime.h>

#define BB 4
#define CC 17
#define NN 4096
#define KN 7
#define NPTS (BB*NN)             // 16384
#define PAIRS (NPTS*KN)          // 114688
#define TT (CC*CC)               // 289
#define FINF 3.4e38f
#define NWV 4                    // waves per knn block
#define CSW 512                  // candidates per wave-slice
#define NTW (CSW/16)             // 32 tiles per wave
#define RPB 16                   // rows per knn block
#define HALF 2048                // candidates per block (half of NN)
#define SCAP 64                  // per-row-half survivor cap
#define SPAD 65                  // 65 mod 32 = 1 -> P3b banks (row+s)%32, conflict-free
#define TDW 160                  // bf16 T row: 320 elems = 160 dwords

typedef float f32x4 __attribute__((ext_vector_type(4)));
typedef short short8 __attribute__((ext_vector_type(8)));

__device__ __forceinline__ unsigned int rne_bf16(float x) {
    unsigned int u = __float_as_uint(x);
    return (u + 0x7FFFu + ((u >> 16) & 1u)) >> 16;
}

__device__ __forceinline__ bool lexless(float ad, int ai, float bd, int bi) {
    return (ad < bd) || (ad == bd && ai < bi);
}

// ---- Stage 1: logits -> xs fp32[.][24], xbA/xbB bf16[.][32] (norm folded), sq
__global__ __launch_bounds__(256) void prep_kernel(const float* __restrict__ logits,
                                                   float* __restrict__ xs,
                                                   unsigned short* __restrict__ xbA,
                                                   unsigned short* __restrict__ xbB,
                                                   float* __restrict__ sq) {
    int i = blockIdx.x * blockDim.x + threadIdx.x;
    if (i >= NPTS) return;
    int b = i >> 12;
    int n = i & (NN - 1);
    const float* base = logits + (size_t)b * CC * NN + n;
    float v[24];
    float s = 0.f;
#pragma unroll
    for (int c = 0; c < CC; ++c) { v[c] = base[(size_t)c * NN]; s = fmaf(v[c], v[c], s); }
#pragma unroll
    for (int c = CC; c < 24; ++c) v[c] = 0.f;
    float4* dst = (float4*)(xs + (size_t)i * 24);
#pragma unroll
    for (int q = 0; q < 6; ++q)
        dst[q] = make_float4(v[4*q], v[4*q+1], v[4*q+2], v[4*q+3]);
    sq[i] = s;

    unsigned int w[16];
#pragma unroll
    for (int t = 0; t < 8; ++t)
        w[t] = rne_bf16(v[2*t]) | (rne_bf16(v[2*t+1]) << 16);
#pragma unroll
    for (int t = 9; t < 16; ++t) w[t] = 0u;
    // A view: slot16 = v16, slot17 = 1.0
    w[8] = rne_bf16(v[16]) | (0x3F80u << 16);
    uint4* da = (uint4*)(xbA + (size_t)i * 32);
#pragma unroll
    for (int q = 0; q < 4; ++q)
        da[q] = make_uint4(w[4*q], w[4*q+1], w[4*q+2], w[4*q+3]);
    // B view: slot17 = -sq/2  => mfma acc = dot - sq_c/2, rank = -2*acc
    w[8] = rne_bf16(v[16]) | (rne_bf16(-0.5f * s) << 16);
    uint4* db = (uint4*)(xbB + (size_t)i * 32);
#pragma unroll
    for (int q = 0; q < 4; ++q)
        db[q] = make_uint4(w[4*q], w[4*q+1], w[4*q+2], w[4*q+3]);
}

// ---- Stage 1b: insT fp32[16384][289] -> Tb bf16[16384][320] ----------------
__global__ __launch_bounds__(256) void prepT_kernel(const float* __restrict__ insT,
                                                    unsigned int* __restrict__ Tb) {
    int i = blockIdx.x * 256 + threadIdx.x;
    int row = i / TDW;
    int dw  = i - row * TDW;
    int e   = dw * 2;
    const float* src = insT + (size_t)row * TT;
    float v0 = (e     < TT) ? src[e]     : 0.f;
    float v1 = (e + 1 < TT) ? src[e + 1] : 0.f;
    Tb[i] = rne_bf16(v0) | (rne_bf16(v1) << 16);
}

// ---- Stage 2: kNN half-sweep. Block = (16-row strip) x (2048-cand half). ---
// 4 waves x 512-cand slices. P1: MFMA sweep, per-lane max -> per-wave
// 8th-of-16-lane-max bound. P2: athr = max wave-bounds - margin; mask sweep ->
// popc append. P3a: fp32 exact rank; P3b: per-row top-8 -> global parts.
__global__ __launch_bounds__(256) void knn_kernel(const unsigned short* __restrict__ xbA,
                                                  const unsigned short* __restrict__ xbB,
                                                  const float* __restrict__ sq,
                                                  const float* __restrict__ xs,
                                                  float* __restrict__ parts_d,
                                                  int* __restrict__ parts_i) {
    int tid   = threadIdx.x;
    int wid   = tid >> 6;
    int lane  = tid & 63;
    int strip = blockIdx.x;              // 0..1023
    int half  = blockIdx.y;              // 0..1
    int b     = strip >> 8;
    int cb    = b * NN + half * HALF + wid * CSW;
    int col   = lane & 15;
    int grp   = lane >> 4;
    int k0    = grp * 8;

    __shared__ float thr_lds[NWV][RPB];
    __shared__ int   scnt[RPB];
    __shared__ int   slist[RPB][SPAD];
    __shared__ float srank[RPB][SPAD];
    if (tid < RPB) scnt[tid] = 0;

    short8 A = *reinterpret_cast<const short8*>(xbA + (size_t)(strip * 16 + col) * 32 + k0);
    const unsigned short* bp = xbB + (size_t)(cb + col) * 32 + k0;
    f32x4 z = {0.f, 0.f, 0.f, 0.f};

    // ---- Pass 1: per-lane stream max of acc (plain loop, compiler pipelines)
    float mx[4] = {-FINF, -FINF, -FINF, -FINF};
#pragma unroll 8
    for (int t = 0; t < NTW; ++t) {
        short8 Bf = *reinterpret_cast<const short8*>(bp + (size_t)t * 512);
        f32x4 acc = __builtin_amdgcn_mfma_f32_16x16x32_bf16(A, Bf, z, 0, 0, 0);
#pragma unroll
        for (int j = 0; j < 4; ++j)
            mx[j] = fmaxf(mx[j], acc[j]);
    }
    // slice bound = 8th-largest of the 16 lane-maxes (flat rank count)
#pragma unroll
    for (int j = 0; j < 4; ++j) {
        float v = mx[j];
        int cnt = 0;
#pragma unroll
        for (int m = 1; m < 16; ++m) {
            float o = __shfl_xor(v, m);
            cnt += (o > v) ? 1 : 0;
        }
        float bv = (cnt <= 7) ? v : FINF;
        bv = fminf(bv, __shfl_xor(bv, 1));
        bv = fminf(bv, __shfl_xor(bv, 2));
        bv = fminf(bv, __shfl_xor(bv, 4));
        bv = fminf(bv, __shfl_xor(bv, 8));
        if (col == 0) thr_lds[wid][grp * 4 + j] = bv;
    }
    __syncthreads();

    // ---- Pass 2: acc-threshold re-sweep -> u32 mask -> popc append ----
    float athr[4];
#pragma unroll
    for (int j = 0; j < 4; ++j) {
        int rr = grp * 4 + j;
        float m = -FINF;
#pragma unroll
        for (int w = 0; w < NWV; ++w) m = fmaxf(m, thr_lds[w][rr]);
        athr[j] = m - (0.35f + 0.007f * fabsf(m));   // bf16-error cover (acc units)
    }
    unsigned int msk[4] = {0u, 0u, 0u, 0u};
#pragma unroll 8
    for (int t = 0; t < NTW; ++t) {
        short8 Bf = *reinterpret_cast<const short8*>(bp + (size_t)t * 512);
        f32x4 acc = __builtin_amdgcn_mfma_f32_16x16x32_bf16(A, Bf, z, 0, 0, 0);
#pragma unroll
        for (int j = 0; j < 4; ++j)
            msk[j] |= (acc[j] > athr[j]) ? (1u << t) : 0u;
    }
#pragma unroll
    for (int j = 0; j < 4; ++j) {
        unsigned int w = msk[j];
        int nb = __popc(w);
        if (nb) {
            int rloc = grp * 4 + j;
            int base = atomicAdd(&scnt[rloc], nb);
            while (w) {
                int t = __ffs(w) - 1; w &= w - 1;
                if (base < SCAP) slist[rloc][base] = cb + t * 16 + col;
                ++base;
            }
        }
    }
    __syncthreads();

    // ---- Pass 3a: exact fp32 rank of survivors; 16 threads per row ----
    {
        int row  = tid >> 4;                 // 0..15
        int l16  = tid & 15;
        int rowg = strip * 16 + row;
        int cnt  = scnt[row]; cnt = (cnt > SCAP) ? SCAP : cnt;
        const float4* qp = (const float4*)(xs + (size_t)rowg * 24);
        float qv[20];
#pragma unroll
        for (int c = 0; c < 5; ++c) {
            float4 t = qp[c];
            qv[4*c] = t.x; qv[4*c+1] = t.y; qv[4*c+2] = t.z; qv[4*c+3] = t.w;
        }
#pragma unroll
        for (int h = 0; h < 4; ++h) {
            int slot = l16 + 16 * h;
            if (slot < cnt) {
                int g = slist[row][slot];
                const float4* xp = (const float4*)(xs + (size_t)g * 24);
                float dot = 0.f;
#pragma unroll
                for (int c = 0; c < 5; ++c) {
                    float4 xv = xp[c];
                    dot = fmaf(qv[4*c+0], xv.x, dot);
                    dot = fmaf(qv[4*c+1], xv.y, dot);
                    dot = fmaf(qv[4*c+2], xv.z, dot);
                    dot = fmaf(qv[4*c+3], xv.w, dot);
                }
                srank[row][slot] = fmaf(-2.f, dot, sq[g]);   // self keeps true rank -sq
            }
        }
    }
    __syncthreads();

    // ---- Pass 3b: 16 lanes (lane = row), serial top-8 -> global parts ----
    if (tid < RPB) {
        int row  = tid;
        int rowg = strip * 16 + row;
        int cnt  = scnt[row]; cnt = (cnt > SCAP) ? SCAP : cnt;
        float bd[8]; int bi[8];
#pragma unroll
        for (int k = 0; k < 8; ++k) { bd[k] = FINF; bi[k] = 0x100000 + (rowg << 4) + k; }
        for (int s = 0; s < cnt; ++s) {
            float r = srank[row][s];
            int   g = slist[row][s];
            if (lexless(r, g, bd[7], bi[7])) {
                bd[7] = r; bi[7] = g;
#pragma unroll
                for (int k = 7; k >= 1; --k) {
                    if (lexless(bd[k], bi[k], bd[k-1], bi[k-1])) {
                        float td = bd[k]; bd[k] = bd[k-1]; bd[k-1] = td;
                        int   ti = bi[k]; bi[k] = bi[k-1]; bi[k-1] = ti;
                    }
                }
            }
        }
        size_t ob = ((size_t)rowg * 2 + half) * 8;
#pragma unroll
        for (int k = 0; k < 8; ++k) { parts_d[ob + k] = bd[k]; parts_i[ob + k] = bi[k]; }
    }
}

// ---- merge prologue (shared): 16 (d,i) entries -> 7 neighbor indices -------
__device__ __forceinline__ void merge7(int row, int lane,
                                       const float* __restrict__ parts_d,
                                       const int* __restrict__ parts_i,
                                       int* jn) {
    float d = FINF;
    int   gi = 0x700000 + lane;
    if (lane < 16) {
        size_t ob = (size_t)row * 16 + lane;
        d  = parts_d[ob];
        gi = parts_i[ob];
        if (gi == row) d = FINF;             // drop self by identity
    }
#pragma unroll
    for (int r = 0; r < KN; ++r) {
        float g = d; int gj = gi;
#pragma unroll
        for (int off = 32; off >= 1; off >>= 1) {
            float od = __shfl_xor(g, off);
            int   oj = __shfl_xor(gj, off);
            if (lexless(od, oj, g, gj)) { g = od; gj = oj; }
        }
        jn[r] = gj;
        if (gi == gj) { d = FINF; gi = 0x780000 + lane * 8 + r; }
    }
}

// ---- Stage 3: wave-per-row: merge + pair terms (bf16 T rows) ---------------
__global__ __launch_bounds__(256) void pairb_kernel(const float* __restrict__ xs,
                                                    const int* __restrict__ labels,
                                                    const unsigned int* __restrict__ Tb,
                                                    const float* __restrict__ parts_d,
                                                    const int* __restrict__ parts_i,
                                                    double* __restrict__ partials) {
    int wid  = threadIdx.x >> 6;
    int lane = threadIdx.x & 63;
    int row  = blockIdx.x * 4 + wid;
    int li   = labels[row];

    int jn[KN];
    merge7(row, lane, parts_d, parts_i, jn);

    const unsigned int* Ti = Tb + (size_t)row * TDW;
    unsigned int a0 = Ti[lane];
    unsigned int a1 = Ti[lane + 64];
    unsigned int a2 = (lane < 32) ? Ti[lane + 128] : 0u;
    float xi = (lane < 20) ? xs[(size_t)row * 24 + lane] : 0.f;

    unsigned int bv[KN][3];
    float xj[KN];
#pragma unroll
    for (int kk = 0; kk < KN; ++kk) {
        const unsigned int* Tj = Tb + (size_t)jn[kk] * TDW;
        bv[kk][0] = Tj[lane];
        bv[kk][1] = Tj[lane + 64];
        bv[kk][2] = (lane < 32) ? Tj[lane + 128] : 0u;
        xj[kk] = (lane < 20) ? xs[(size_t)jn[kk] * 24 + lane] : 0.f;
    }

    double acc = 0.0;
#pragma unroll
    for (int kk = 0; kk < KN; ++kk) {
        float td = 0.f;
        unsigned int aw[3] = {a0, a1, a2};
#pragma unroll
        for (int q = 0; q < 3; ++q) {
            unsigned int a = aw[q], bb = bv[kk][q];
            float dlo = __uint_as_float(a << 16)         - __uint_as_float(bb << 16);
            float dhi = __uint_as_float(a & 0xFFFF0000u) - __uint_as_float(bb & 0xFFFF0000u);
            td = fmaf(dlo, dlo, td);
            td = fmaf(dhi, dhi, td);
        }
        float df = xi - xj[kk];
        float dp = df * df;
#pragma unroll
        for (int off = 32; off >= 1; off >>= 1) {
            td += __shfl_xor(td, off);
            dp += __shfl_xor(dp, off);
        }
        if (lane == 0) {
            float eij = expf(-0.5f * dp);
            float sgn = (labels[jn[kk]] == li) ? eij : -eij;
            acc += (double)sgn * (double)td;
        }
    }
    __shared__ double wsum[4];
    if (lane == 0) wsum[wid] = acc;
    __syncthreads();
    if (threadIdx.x == 0)
        partials[blockIdx.x] = wsum[0] + wsum[1] + wsum[2] + wsum[3];
}

// ---- Stage 3': fp32 fallback (small workspace) -----------------------------
__global__ __launch_bounds__(256) void pair_f32_kernel(const float* __restrict__ xs,
                                                       const int* __restrict__ labels,
                                                       const float* __restrict__ insT,
                                                       const float* __restrict__ parts_d,
                                                       const int* __restrict__ parts_i,
                                                       double* __restrict__ partials) {
    int wid  = threadIdx.x >> 6;
    int lane = threadIdx.x & 63;
    int row  = blockIdx.x * 4 + wid;
    int li   = labels[row];

    int jn[KN];
    merge7(row, lane, parts_d, parts_i, jn);

    const float* Ti = insT + (size_t)row * TT;
    float tiv[5];
#pragma unroll
    for (int q = 0; q < 5; ++q) {
        int e = lane + 64 * q;
        tiv[q] = (e < TT) ? Ti[e] : 0.f;
    }
    float xi = (lane < 20) ? xs[(size_t)row * 24 + lane] : 0.f;
    double acc = 0.0;
#pragma unroll 1
    for (int kk = 0; kk < KN; ++kk) {
        int j = jn[kk];
        const float* Tj = insT + (size_t)j * TT;
        float td = 0.f;
#pragma unroll
        for (int q = 0; q < 5; ++q) {
            int e = lane + 64 * q;
            if (e < TT) { float df = tiv[q] - Tj[e]; td = fmaf(df, df, td); }
        }
        float dp = 0.f;
        if (lane < 20) { float df = xi - xs[(size_t)j * 24 + lane]; dp = df * df; }
#pragma unroll
        for (int off = 32; off >= 1; off >>= 1) {
            td += __shfl_xor(td, off);
            dp += __shfl_xor(dp, off);
        }
        if (lane == 0) {
            float eij = expf(-0.5f * dp);
            float sgn = (labels[j] == li) ? eij : -eij;
            acc += (double)sgn * (double)td;
        }
    }
    __shared__ double wsum[4];
    if (lane == 0) wsum[wid] = acc;
    __syncthreads();
    if (threadIdx.x == 0)
        partials[blockIdx.x] = wsum[0] + wsum[1] + wsum[2] + wsum[3];
}

// ---- Stage 4: deterministic final reduce + mean ----------------------------
__global__ __launch_bounds__(1024) void finalize_kernel(const double* __restrict__ partials,
                                                        int nparts, float* __restrict__ out) {
    __shared__ double red[1024];
    int t = threadIdx.x;
    double s = 0.0;
    for (int q = t; q < nparts; q += 1024) s += partials[q];
    red[t] = s;
    __syncthreads();
    for (int sft = 512; sft > 0; sft >>= 1) {
        if (t < sft) red[t] += red[t + sft];
        __syncthreads();
    }
    if (t == 0) out[0] = (float)(red[0] / (double)PAIRS);
}

extern "C" void kernel_launch(void* const* d_in, const int* in_sizes, int n_in,
                              void* d_out, int out_size, void* d_ws, size_t ws_size,
                              hipStream_t stream) {
    const float* logits = (const float*)d_in[0];
    const int*   labels = (const int*)d_in[1];
    const float* insT   = (const float*)d_in[2];
    float* out = (float*)d_out;

    // workspace layout (bytes)
    const size_t o_part = 0;                          // 32768
    const size_t o_pd   = 32768;                      // parts_d 16384*16*4 = 1 MB
    const size_t o_pi   = o_pd + 1048576;             // parts_i 1 MB
    const size_t o_sq   = o_pi + 1048576;             // 65536
    const size_t o_xs   = o_sq + 65536;               // 1572864
    const size_t o_xbA  = o_xs + 1572864;             // 1048576
    const size_t o_xbB  = o_xbA + 1048576;            // 1048576
    const size_t o_Tb   = o_xbB + 1048576;            // 10485760
    const size_t need_Tb = o_Tb + 10485760;           // ~16.3 MB

    char* ws = (char*)d_ws;
    double*         partials = (double*)(ws + o_part);
    float*          parts_d  = (float*)(ws + o_pd);
    int*            parts_i  = (int*)(ws + o_pi);
    float*          sq       = (float*)(ws + o_sq);
    float*          xs       = (float*)(ws + o_xs);
    unsigned short* xbA      = (unsigned short*)(ws + o_xbA);
    unsigned short* xbB      = (unsigned short*)(ws + o_xbB);
    unsigned int*   Tb       = (unsigned int*)(ws + o_Tb);

    bool useTb = (ws_size >= need_Tb);

    hipLaunchKernelGGL(prep_kernel, dim3(NPTS / 256), dim3(256), 0, stream,
                       logits, xs, xbA, xbB, sq);
    if (useTb)
        hipLaunchKernelGGL(prepT_kernel, dim3(NPTS * TDW / 256), dim3(256), 0, stream,
                           insT, Tb);
    hipLaunchKernelGGL(knn_kernel, dim3(NPTS / RPB, 2), dim3(256), 0, stream,
                       xbA, xbB, sq, xs, parts_d, parts_i);
    if (useTb)
        hipLaunchKernelGGL(pairb_kernel, dim3(NPTS / 4), dim3(256), 0, stream,
                           xs, labels, Tb, parts_d, parts_i, partials);
    else
        hipLaunchKernelGGL(pair_f32_kernel, dim3(NPTS / 4), dim3(256), 0, stream,
                           xs, labels, insT, parts_d, parts_i, partials);
    hipLaunchKernelGGL(finalize_kernel, dim3(1), dim3(1024), 0, stream,
                       partials, NPTS / 4, out);
}

// Round 13
// 98.230 us; speedup vs baseline: 3.6504x; 1.4552x over previous
//
#include <hip/hip_runtime.h>

#define BB 4
#define CC 17
#define NN 4096
#define KN 7
#define NPTS (BB*NN)             // 16384
#define PAIRS (NPTS*KN)          // 114688
#define TT (CC*CC)               // 289
#define FINF 3.4e38f
#define RPB 64                   // rows per knn block (4 strips of 16)
#define HALF 2048                // candidates per half-stream
#define TPH 128                  // tiles per half (2048/16)
#define NCH 16                   // chunks per pass (8 tiles each)
#define SCAP 48                  // per-row survivor cap
#define SPAD 49                  // 49 mod 32 = 17 (odd) -> P3b 2-way max, free
#define TDW 160                  // bf16 T row: 320 elems = 160 dwords

typedef float f32x4 __attribute__((ext_vector_type(4)));
typedef short short8 __attribute__((ext_vector_type(8)));

__device__ __forceinline__ unsigned int rne_bf16(float x) {
    unsigned int u = __float_as_uint(x);
    return (u + 0x7FFFu + ((u >> 16) & 1u)) >> 16;
}

__device__ __forceinline__ bool lexless(float ad, int ai, float bd, int bi) {
    return (ad < bd) || (ad == bd && ai < bi);
}

// ---- Stage 1: logits -> xs fp32[.][24], xbA/xbB bf16[.][32] (norm folded), sq
__global__ __launch_bounds__(256) void prep_kernel(const float* __restrict__ logits,
                                                   float* __restrict__ xs,
                                                   unsigned short* __restrict__ xbA,
                                                   unsigned short* __restrict__ xbB,
                                                   float* __restrict__ sq) {
    int i = blockIdx.x * blockDim.x + threadIdx.x;
    if (i >= NPTS) return;
    int b = i >> 12;
    int n = i & (NN - 1);
    const float* base = logits + (size_t)b * CC * NN + n;
    float v[24];
    float s = 0.f;
#pragma unroll
    for (int c = 0; c < CC; ++c) { v[c] = base[(size_t)c * NN]; s = fmaf(v[c], v[c], s); }
#pragma unroll
    for (int c = CC; c < 24; ++c) v[c] = 0.f;
    float4* dst = (float4*)(xs + (size_t)i * 24);
#pragma unroll
    for (int q = 0; q < 6; ++q)
        dst[q] = make_float4(v[4*q], v[4*q+1], v[4*q+2], v[4*q+3]);
    sq[i] = s;

    unsigned int w[16];
#pragma unroll
    for (int t = 0; t < 8; ++t)
        w[t] = rne_bf16(v[2*t]) | (rne_bf16(v[2*t+1]) << 16);
#pragma unroll
    for (int t = 9; t < 16; ++t) w[t] = 0u;
    // A view: slot16 = v16, slot17 = 1.0
    w[8] = rne_bf16(v[16]) | (0x3F80u << 16);
    uint4* da = (uint4*)(xbA + (size_t)i * 32);
#pragma unroll
    for (int q = 0; q < 4; ++q)
        da[q] = make_uint4(w[4*q], w[4*q+1], w[4*q+2], w[4*q+3]);
    // B view: slot17 = -sq/2  => mfma acc = dot - sq_c/2, rank = -2*acc
    w[8] = rne_bf16(v[16]) | (rne_bf16(-0.5f * s) << 16);
    uint4* db = (uint4*)(xbB + (size_t)i * 32);
#pragma unroll
    for (int q = 0; q < 4; ++q)
        db[q] = make_uint4(w[4*q], w[4*q+1], w[4*q+2], w[4*q+3]);
}

// ---- Stage 1b: insT fp32[16384][289] -> Tb bf16[16384][320] ----------------
__global__ __launch_bounds__(256) void prepT_kernel(const float* __restrict__ insT,
                                                    unsigned int* __restrict__ Tb) {
    int i = blockIdx.x * 256 + threadIdx.x;
    int row = i / TDW;
    int dw  = i - row * TDW;
    int e   = dw * 2;
    const float* src = insT + (size_t)row * TT;
    float v0 = (e     < TT) ? src[e]     : 0.f;
    float v1 = (e + 1 < TT) ? src[e + 1] : 0.f;
    Tb[i] = rne_bf16(v0) | (rne_bf16(v1) << 16);
}

// ---- Stage 2: fused kNN with LDS-shared candidate stream -------------------
// Block = 64 rows x 8 waves. Wave (s,h): strip s (16 rows) vs half h (2048 c).
// Candidate tiles staged in LDS (8-tile chunks, double-buffered); each tile
// loaded from L2 ONCE and consumed by the 4 waves sharing that half-stream.
// P1: max-acc sweep -> per-(strip,half) 8th-of-16-lane-max bound.
// P2: thr = max over halves - margin; mask sweep -> LDS survivor append.
// P3a: exact fp32 re-rank (8 thr/row); P3b: 64-lane serial top-7 -> nidx.
__global__ __launch_bounds__(512) void knn_kernel(const unsigned short* __restrict__ xbA,
                                                  const unsigned short* __restrict__ xbB,
                                                  const float* __restrict__ sq,
                                                  const float* __restrict__ xs,
                                                  int* __restrict__ nidx) {
    int tid  = threadIdx.x;
    int wid  = tid >> 6;
    int lane = tid & 63;
    int s    = wid >> 1;                 // strip 0..3
    int h    = wid & 1;                  // half 0..1
    int row0 = blockIdx.x * RPB;
    int b    = row0 >> 12;
    int myrow = row0 + s * 16;
    int cb   = b * NN + h * HALF;
    int col  = lane & 15;
    int grp  = lane >> 4;
    int k0   = grp * 8;

    __shared__ short8 stg[2][2][8][64];  // [half][buf][tile][lane] = 32 KB
    __shared__ float  bnd[2][RPB];
    __shared__ int    scnt[RPB];
    __shared__ int    slist[RPB][SPAD];
    __shared__ float  srank[RPB][SPAD];
    if (tid < RPB) scnt[tid] = 0;

    short8 A = *reinterpret_cast<const short8*>(xbA + (size_t)(myrow + col) * 32 + k0);
    // staging source: fragment-order bytes for this lane
    const char* gb = (const char*)xbB + (size_t)cb * 64;
    int lanebytes = col * 64 + grp * 16;
    int t0 = 2 * s;                      // this wave stages tiles 2s, 2s+1 of each chunk
    f32x4 z = {0.f, 0.f, 0.f, 0.f};

    // =============== PASS 1: per-row max-acc ===============
    float mx[4] = {-FINF, -FINF, -FINF, -FINF};
    {
        // prologue: stage chunk 0 -> buf 0
        uint4 d0 = *(const uint4*)(gb + (size_t)(t0) * 1024 + lanebytes);
        uint4 d1 = *(const uint4*)(gb + (size_t)(t0 + 1) * 1024 + lanebytes);
        *(uint4*)&stg[h][0][t0][lane]     = d0;
        *(uint4*)&stg[h][0][t0 + 1][lane] = d1;
    }
    __syncthreads();
    for (int c = 0; c < NCH; ++c) {
        int f = c & 1;
        uint4 d0, d1;
        if (c + 1 < NCH) {               // issue next-chunk loads EARLY
            d0 = *(const uint4*)(gb + (size_t)((c + 1) * 8 + t0) * 1024 + lanebytes);
            d1 = *(const uint4*)(gb + (size_t)((c + 1) * 8 + t0 + 1) * 1024 + lanebytes);
        }
#pragma unroll
        for (int u = 0; u < 8; ++u) {
            short8 Bf = stg[h][f][u][lane];
            f32x4 acc = __builtin_amdgcn_mfma_f32_16x16x32_bf16(A, Bf, z, 0, 0, 0);
#pragma unroll
            for (int j = 0; j < 4; ++j)
                mx[j] = fmaxf(mx[j], acc[j]);
        }
        if (c + 1 < NCH) {               // write LATE (loads landed under consume)
            *(uint4*)&stg[h][f ^ 1][t0][lane]     = d0;
            *(uint4*)&stg[h][f ^ 1][t0 + 1][lane] = d1;
        }
        __syncthreads();
    }
    // per-(strip,half) bound = 8th-largest of the 16 lane-maxes (flat rank)
#pragma unroll
    for (int j = 0; j < 4; ++j) {
        float v = mx[j];
        int cnt = 0;
#pragma unroll
        for (int m = 1; m < 16; ++m) {
            float o = __shfl_xor(v, m);
            cnt += (o > v) ? 1 : 0;
        }
        float bv = (cnt <= 7) ? v : FINF;
        bv = fminf(bv, __shfl_xor(bv, 1));
        bv = fminf(bv, __shfl_xor(bv, 2));
        bv = fminf(bv, __shfl_xor(bv, 4));
        bv = fminf(bv, __shfl_xor(bv, 8));
        if (col == 0) bnd[h][s * 16 + grp * 4 + j] = bv;
    }
    __syncthreads();

    // =============== PASS 2: threshold mask + append ===============
    float athr[4];
#pragma unroll
    for (int j = 0; j < 4; ++j) {
        int idx = s * 16 + grp * 4 + j;
        float m = fmaxf(bnd[0][idx], bnd[1][idx]);
        athr[j] = m - (0.35f + 0.007f * fabsf(m));   // bf16-error cover (acc units)
    }
    {
        uint4 d0 = *(const uint4*)(gb + (size_t)(t0) * 1024 + lanebytes);
        uint4 d1 = *(const uint4*)(gb + (size_t)(t0 + 1) * 1024 + lanebytes);
        *(uint4*)&stg[h][0][t0][lane]     = d0;
        *(uint4*)&stg[h][0][t0 + 1][lane] = d1;
    }
    __syncthreads();
    for (int c = 0; c < NCH; ++c) {
        int f = c & 1;
        uint4 d0, d1;
        if (c + 1 < NCH) {
            d0 = *(const uint4*)(gb + (size_t)((c + 1) * 8 + t0) * 1024 + lanebytes);
            d1 = *(const uint4*)(gb + (size_t)((c + 1) * 8 + t0 + 1) * 1024 + lanebytes);
        }
        unsigned int m8[4] = {0u, 0u, 0u, 0u};
#pragma unroll
        for (int u = 0; u < 8; ++u) {
            short8 Bf = stg[h][f][u][lane];
            f32x4 acc = __builtin_amdgcn_mfma_f32_16x16x32_bf16(A, Bf, z, 0, 0, 0);
#pragma unroll
            for (int j = 0; j < 4; ++j)
                m8[j] |= (acc[j] > athr[j]) ? (1u << u) : 0u;
        }
#pragma unroll
        for (int j = 0; j < 4; ++j) {
            unsigned int w = m8[j];
            int nb = __popc(w);
            if (nb) {
                int rloc = s * 16 + grp * 4 + j;
                int bse = atomicAdd(&scnt[rloc], nb);
                while (w) {
                    int u = __ffs(w) - 1; w &= w - 1;
                    if (bse < SCAP) slist[rloc][bse] = cb + (c * 8 + u) * 16 + col;
                    ++bse;
                }
            }
        }
        if (c + 1 < NCH) {
            *(uint4*)&stg[h][f ^ 1][t0][lane]     = d0;
            *(uint4*)&stg[h][f ^ 1][t0 + 1][lane] = d1;
        }
        __syncthreads();
    }

    // ---- Pass 3a: exact fp32 rank of survivors; 8 threads per row ----
    {
        int rowl = tid >> 3;                 // 0..63
        int l8   = tid & 7;
        int rowg = row0 + rowl;
        int cnt  = scnt[rowl]; cnt = (cnt > SCAP) ? SCAP : cnt;
        const float4* qp = (const float4*)(xs + (size_t)rowg * 24);
        float qv[20];
#pragma unroll
        for (int c = 0; c < 5; ++c) {
            float4 t = qp[c];
            qv[4*c] = t.x; qv[4*c+1] = t.y; qv[4*c+2] = t.z; qv[4*c+3] = t.w;
        }
#pragma unroll
        for (int hh = 0; hh < 6; ++hh) {
            int slot = l8 + 8 * hh;
            if (slot < cnt) {
                int g = slist[rowl][slot];
                const float4* xp = (const float4*)(xs + (size_t)g * 24);
                float dot = 0.f;
#pragma unroll
                for (int c = 0; c < 5; ++c) {
                    float4 xv = xp[c];
                    dot = fmaf(qv[4*c+0], xv.x, dot);
                    dot = fmaf(qv[4*c+1], xv.y, dot);
                    dot = fmaf(qv[4*c+2], xv.z, dot);
                    dot = fmaf(qv[4*c+3], xv.w, dot);
                }
                float r = fmaf(-2.f, dot, sq[g]);
                if (g == rowg) r = FINF;     // drop self by identity
                srank[rowl][slot] = r;
            }
        }
    }
    __syncthreads();

    // ---- Pass 3b: 64 lanes (lane = row), serial top-7 over cnt entries ----
    if (tid < RPB) {
        int rowl = tid;
        int rowg = row0 + rowl;
        int cnt  = scnt[rowl]; cnt = (cnt > SCAP) ? SCAP : cnt;
        float bd[KN]; int bi[KN];
#pragma unroll
        for (int k = 0; k < KN; ++k) { bd[k] = FINF; bi[k] = rowg; }
        for (int ss = 0; ss < cnt; ++ss) {
            float r = srank[rowl][ss];
            int   g = slist[rowl][ss];
            if (lexless(r, g, bd[KN-1], bi[KN-1])) {
                bd[KN-1] = r; bi[KN-1] = g;
#pragma unroll
                for (int k = KN - 1; k >= 1; --k) {
                    if (lexless(bd[k], bi[k], bd[k-1], bi[k-1])) {
                        float td = bd[k]; bd[k] = bd[k-1]; bd[k-1] = td;
                        int   ti = bi[k]; bi[k] = bi[k-1]; bi[k-1] = ti;
                    }
                }
            }
        }
#pragma unroll
        for (int k = 0; k < KN; ++k)
            nidx[(size_t)rowg * KN + k] = bi[k];
    }
}

// ---- Stage 3: wave-per-row pair terms, bf16 T rows, XCD-swizzled ----------
__global__ __launch_bounds__(256) void pairb_kernel(const float* __restrict__ xs,
                                                    const int* __restrict__ labels,
                                                    const unsigned int* __restrict__ Tb,
                                                    const int* __restrict__ nidx,
                                                    double* __restrict__ partials) {
    int wid  = threadIdx.x >> 6;
    int lane = threadIdx.x & 63;
    int bid  = blockIdx.x;                     // 4096 blocks, 4096%8==0 -> bijective
    int bswz = (bid & 7) * 512 + (bid >> 3);   // XCD-chunked: L2-local Tb slices
    int row  = bswz * 4 + wid;
    int li   = labels[row];

    const unsigned int* Ti = Tb + (size_t)row * TDW;
    unsigned int a0 = Ti[lane];
    unsigned int a1 = Ti[lane + 64];
    unsigned int a2 = (lane < 32) ? Ti[lane + 128] : 0u;
    float xi = (lane < 20) ? xs[(size_t)row * 24 + lane] : 0.f;

    int jn[KN];
#pragma unroll
    for (int kk = 0; kk < KN; ++kk) jn[kk] = nidx[(size_t)row * KN + kk];

    unsigned int bv[KN][3];
    float xj[KN];
#pragma unroll
    for (int kk = 0; kk < KN; ++kk) {
        const unsigned int* Tj = Tb + (size_t)jn[kk] * TDW;
        bv[kk][0] = Tj[lane];
        bv[kk][1] = Tj[lane + 64];
        bv[kk][2] = (lane < 32) ? Tj[lane + 128] : 0u;
        xj[kk] = (lane < 20) ? xs[(size_t)jn[kk] * 24 + lane] : 0.f;
    }

    double acc = 0.0;
#pragma unroll
    for (int kk = 0; kk < KN; ++kk) {
        float td = 0.f;
        unsigned int aw[3] = {a0, a1, a2};
#pragma unroll
        for (int q = 0; q < 3; ++q) {
            unsigned int a = aw[q], bb = bv[kk][q];
            float dlo = __uint_as_float(a << 16)         - __uint_as_float(bb << 16);
            float dhi = __uint_as_float(a & 0xFFFF0000u) - __uint_as_float(bb & 0xFFFF0000u);
            td = fmaf(dlo, dlo, td);
            td = fmaf(dhi, dhi, td);
        }
        float df = xi - xj[kk];
        float dp = df * df;
#pragma unroll
        for (int off = 32; off >= 1; off >>= 1) {
            td += __shfl_xor(td, off);
            dp += __shfl_xor(dp, off);
        }
        if (lane == 0) {
            float eij = expf(-0.5f * dp);
            float sgn = (labels[jn[kk]] == li) ? eij : -eij;
            acc += (double)sgn * (double)td;
        }
    }
    __shared__ double wsum[4];
    if (lane == 0) wsum[wid] = acc;
    __syncthreads();
    if (threadIdx.x == 0)
        partials[blockIdx.x] = wsum[0] + wsum[1] + wsum[2] + wsum[3];
}

// ---- Stage 3': fp32 fallback (small workspace) -----------------------------
__global__ __launch_bounds__(256) void pair_f32_kernel(const float* __restrict__ xs,
                                                       const int* __restrict__ labels,
                                                       const float* __restrict__ insT,
                                                       const int* __restrict__ nidx,
                                                       double* __restrict__ partials) {
    int wid  = threadIdx.x >> 6;
    int lane = threadIdx.x & 63;
    int bid  = blockIdx.x;
    int bswz = (bid & 7) * 512 + (bid >> 3);
    int row  = bswz * 4 + wid;
    int li   = labels[row];
    const float* Ti = insT + (size_t)row * TT;
    float tiv[5];
#pragma unroll
    for (int q = 0; q < 5; ++q) {
        int e = lane + 64 * q;
        tiv[q] = (e < TT) ? Ti[e] : 0.f;
    }
    float xi = (lane < 20) ? xs[(size_t)row * 24 + lane] : 0.f;
    double acc = 0.0;
#pragma unroll 1
    for (int kk = 0; kk < KN; ++kk) {
        int j = nidx[(size_t)row * KN + kk];
        const float* Tj = insT + (size_t)j * TT;
        float td = 0.f;
#pragma unroll
        for (int q = 0; q < 5; ++q) {
            int e = lane + 64 * q;
            if (e < TT) { float df = tiv[q] - Tj[e]; td = fmaf(df, df, td); }
        }
        float dp = 0.f;
        if (lane < 20) { float df = xi - xs[(size_t)j * 24 + lane]; dp = df * df; }
#pragma unroll
        for (int off = 32; off >= 1; off >>= 1) {
            td += __shfl_xor(td, off);
            dp += __shfl_xor(dp, off);
        }
        if (lane == 0) {
            float eij = expf(-0.5f * dp);
            float sgn = (labels[j] == li) ? eij : -eij;
            acc += (double)sgn * (double)td;
        }
    }
    __shared__ double wsum[4];
    if (lane == 0) wsum[wid] = acc;
    __syncthreads();
    if (threadIdx.x == 0)
        partials[blockIdx.x] = wsum[0] + wsum[1] + wsum[2] + wsum[3];
}

// ---- Stage 4: deterministic final reduce + mean ----------------------------
__global__ __launch_bounds__(1024) void finalize_kernel(const double* __restrict__ partials,
                                                        int nparts, float* __restrict__ out) {
    __shared__ double red[1024];
    int t = threadIdx.x;
    double s = 0.0;
    for (int q = t; q < nparts; q += 1024) s += partials[q];
    red[t] = s;
    __syncthreads();
    for (int sft = 512; sft > 0; sft >>= 1) {
        if (t < sft) red[t] += red[t + sft];
        __syncthreads();
    }
    if (t == 0) out[0] = (float)(red[0] / (double)PAIRS);
}

extern "C" void kernel_launch(void* const* d_in, const int* in_sizes, int n_in,
                              void* d_out, int out_size, void* d_ws, size_t ws_size,
                              hipStream_t stream) {
    const float* logits = (const float*)d_in[0];
    const int*   labels = (const int*)d_in[1];
    const float* insT   = (const float*)d_in[2];
    float* out = (float*)d_out;

    // workspace layout (bytes)
    const size_t o_part = 0;                          // 32768
    const size_t o_nidx = 32768;                      // 458752
    const size_t o_sq   = o_nidx + 458752;            // 65536
    const size_t o_xs   = o_sq + 65536;               // 1572864
    const size_t o_xbA  = o_xs + 1572864;             // 1048576
    const size_t o_xbB  = o_xbA + 1048576;            // 1048576
    const size_t o_Tb   = o_xbB + 1048576;            // 10485760
    const size_t need_Tb = o_Tb + 10485760;           // ~14.7 MB

    char* ws = (char*)d_ws;
    double*         partials = (double*)(ws + o_part);
    int*            nidx     = (int*)(ws + o_nidx);
    float*          sq       = (float*)(ws + o_sq);
    float*          xs       = (float*)(ws + o_xs);
    unsigned short* xbA      = (unsigned short*)(ws + o_xbA);
    unsigned short* xbB      = (unsigned short*)(ws + o_xbB);
    unsigned int*   Tb       = (unsigned int*)(ws + o_Tb);

    bool useTb = (ws_size >= need_Tb);

    hipLaunchKernelGGL(prep_kernel, dim3(NPTS / 256), dim3(256), 0, stream,
                       logits, xs, xbA, xbB, sq);
    if (useTb)
        hipLaunchKernelGGL(prepT_kernel, dim3(NPTS * TDW / 256), dim3(256), 0, stream,
                           insT, Tb);
    hipLaunchKernelGGL(knn_kernel, dim3(NPTS / RPB), dim3(512), 0, stream,
                       xbA, xbB, sq, xs, nidx);
    if (useTb)
        hipLaunchKernelGGL(pairb_kernel, dim3(NPTS / 4), dim3(256), 0, stream,
                           xs, labels, Tb, nidx, partials);
    else
        hipLaunchKernelGGL(pair_f32_kernel, dim3(NPTS / 4), dim3(256), 0, stream,
                           xs, labels, insT, nidx, partials);
    hipLaunchKernelGGL(finalize_kernel, dim3(1), dim3(1024), 0, stream,
                       partials, NPTS / 4, out);
}